// Round 18
// baseline (168.768 us; speedup 1.0000x reference)
//
#include <hip/hip_runtime.h>
#include <math.h>

#define DM 1024
#define DI 2048
#define NS 16
#define DTR 64
#define LL 2048
#define NXDBL 96      // DTR + 2*NS
#define NCHUNK 128
#define CHLEN 16      // LL / NCHUNK
#define NSUPER 16
#define SUBCH 8       // NCHUNK / NSUPER

typedef unsigned short u16;
typedef __attribute__((ext_vector_type(8))) short short8;
typedef __attribute__((ext_vector_type(8))) unsigned short us8;
typedef __attribute__((ext_vector_type(4))) float f32x4;

__device__ __forceinline__ float sigmoidf_(float x) { return 1.f / (1.f + __expf(-x)); }
__device__ __forceinline__ float siluf_(float x) { return x * sigmoidf_(x); }
__device__ __forceinline__ float softplus_fast(float x) {
    return fmaxf(x, 0.f) + __logf(1.f + __expf(-fabsf(x)));
}
__device__ __forceinline__ u16 f2b(float f) {  // fp32 -> bf16 RNE
    unsigned u = __float_as_uint(f);
    return (u16)((u + 0x7FFFu + ((u >> 16) & 1u)) >> 16);
}
__device__ __forceinline__ float b2f(u16 h) {
    return __uint_as_float(((unsigned)h) << 16);
}
__device__ __forceinline__ unsigned pack2(float lo, float hi) {
    return (unsigned)f2b(lo) | ((unsigned)f2b(hi) << 16);
}

// ---------------- fused prep: x->bf16, W_in^T, W_out^T, W_x^T + zero-pad --------
__device__ __forceinline__ void convT_dev(const float* __restrict__ src,
                                          u16* __restrict__ dst, int R, int C,
                                          int bflat, int gridx, float (*t)[33]) {
    const int tx = threadIdx.x & 31, ty = threadIdx.x >> 5;  // ty 0..7
    const int c0 = (bflat % gridx) * 32, r0 = (bflat / gridx) * 32;
#pragma unroll
    for (int i = 0; i < 4; i++)
        t[ty + i * 8][tx] = src[(size_t)(r0 + ty + i * 8) * C + c0 + tx];
    __syncthreads();
#pragma unroll
    for (int i = 0; i < 4; i++)
        dst[(size_t)(c0 + ty + i * 8) * R + r0 + tx] = f2b(t[tx][ty + i * 8]);
}

// block ranges: [0,2048) x-convert | [2048,6144) W_in^T | [6144,8192) W_out^T |
//               [8192,8384) W_x^T | [8384,8640) zero-pad rows 96..127
#define PREP_BLOCKS 8640
__global__ __launch_bounds__(256) void prep_all(const float* __restrict__ x,
                                                u16* __restrict__ xb,
                                                const float* __restrict__ W_in,
                                                u16* __restrict__ W_inT,
                                                const float* __restrict__ W_out,
                                                u16* __restrict__ W_outT,
                                                const float* __restrict__ W_x,
                                                u16* __restrict__ W_xT_pad) {
    __shared__ float t[32][33];
    const int b = blockIdx.x;
    if (b < 2048) {
        const int i = (b * 256 + threadIdx.x) * 4;
        float4 v = *(const float4*)&x[i];
        u16 o[4] = {f2b(v.x), f2b(v.y), f2b(v.z), f2b(v.w)};
        *(ushort4*)&xb[i] = *(ushort4*)o;
    } else if (b < 6144) {
        convT_dev(W_in, W_inT, DM, 2 * DI, b - 2048, 2 * DI / 32, t);
    } else if (b < 8192) {
        convT_dev(W_out, W_outT, DI, DM, b - 6144, DM / 32, t);
    } else if (b < 8384) {
        convT_dev(W_x, W_xT_pad, DI, NXDBL, b - 8192, NXDBL / 32, t);
    } else {
        const int i = (b - 8384) * 256 + threadIdx.x;
        if (i < 32 * DI) W_xT_pad[96 * DI + i] = 0;
    }
}

// ---------------- bf16 MFMA GEMM: C[M][N] = A[M][K] @ Bt[N][K]^T -----------------
// 128x128 tile, BK=32, K = NSTEPS*32. 3-buffer LDS pipeline, prefetch distance 2,
// counted s_waitcnt vmcnt(N) + raw s_barrier. LDS k-group XOR swizzle on the
// per-lane GLOBAL source (write) and the ds_read offset (read); LDS stays linear.
// XCD-aware block swizzle: flat id -> (h&7)*(nb/8)+(h>>3), column-major decompose.
// EPI==1: cols [0,DI) -> C0 bf16 (xc); cols [DI,2DI) -> C1 bf16 = silu(v) (gate).
// EPI==0: fp32 partial to (float*)C0 + z*M*nreal, ld=nreal, store iff col<nreal.
// EPI==2: bf16 partial to (u16*)C0 + z*M*nreal, ld=nreal.
#define WAITV(N) asm volatile("s_waitcnt vmcnt(" #N ")" ::: "memory")
template <int EPI, int NSTEPS>
__global__ __launch_bounds__(256) void gemm_mfma(const u16* __restrict__ A,
                                                 const u16* __restrict__ Bt,
                                                 void* __restrict__ C0,
                                                 void* __restrict__ C1,
                                                 int M, int N, int lda, int nreal) {
    __shared__ u16 As[3][128 * 32];
    __shared__ u16 Bs[3][128 * 32];
    const int tid = threadIdx.x;
    const int lane = tid & 63;
    const int wave = tid >> 6;
    // XCD-aware swizzle (bijective; nb multiple of 8)
    const int gx = gridDim.x, gy = gridDim.y;
    const int nb = gx * gy;
    const int h = blockIdx.y * gx + blockIdx.x;
    const int f = (h & 7) * (nb >> 3) + (h >> 3);
    const int bm = (f % gy) * 128, bn = (f / gy) * 128;
    const int wr = wave >> 1, wc = wave & 1;
    const int k_off = blockIdx.z * (NSTEPS * 32);

    f32x4 acc[4][4];
#pragma unroll
    for (int m = 0; m < 4; m++)
#pragma unroll
        for (int n = 0; n < 4; n++) acc[m][n] = (f32x4)0.f;

    // staging: thread tid -> (row = tid>>2, kg = tid&3), LDS linear at tid*16B.
    const int srow = tid >> 2;
    const int swz = (tid >> 3) & 3;                    // (srow>>1)&3
    const int skel = (((tid & 3) ^ swz) << 3);         // swizzled k elem offset
    const u16* Ag0 = A + (size_t)(bm + srow) * lda + k_off + skel;
    const u16* Ag1 = A + (size_t)(bm + 64 + srow) * lda + k_off + skel;
    const u16* Bg0 = Bt + (size_t)(bn + srow) * lda + k_off + skel;
    const u16* Bg1 = Bt + (size_t)(bn + 64 + srow) * lda + k_off + skel;
    u16* Asl = &As[0][0] + tid * 8;
    u16* Bsl = &Bs[0][0] + tid * 8;

    // fragment read offsets (u16 units), same swizzle on the kg index
    const int rsw = (lane >> 1) & 3;                   // row bits 1-2
    const int arow = (wr * 64 + (lane & 15)) * 32 + (((lane >> 4) ^ rsw) << 3);
    const int brow = (wc * 64 + (lane & 15)) * 32 + (((lane >> 4) ^ rsw) << 3);

#define STAGE(buf, ks)                                                               \
    do {                                                                             \
        __builtin_amdgcn_global_load_lds(                                            \
            (const __attribute__((address_space(1))) unsigned*)(Ag0 + (ks)),         \
            (__attribute__((address_space(3))) unsigned*)(Asl + (buf) * 4096),       \
            16, 0, 0);                                                               \
        __builtin_amdgcn_global_load_lds(                                            \
            (const __attribute__((address_space(1))) unsigned*)(Ag1 + (ks)),         \
            (__attribute__((address_space(3))) unsigned*)(Asl + (buf) * 4096 + 2048),\
            16, 0, 0);                                                               \
        __builtin_amdgcn_global_load_lds(                                            \
            (const __attribute__((address_space(1))) unsigned*)(Bg0 + (ks)),         \
            (__attribute__((address_space(3))) unsigned*)(Bsl + (buf) * 4096),       \
            16, 0, 0);                                                               \
        __builtin_amdgcn_global_load_lds(                                            \
            (const __attribute__((address_space(1))) unsigned*)(Bg1 + (ks)),         \
            (__attribute__((address_space(3))) unsigned*)(Bsl + (buf) * 4096 + 2048),\
            16, 0, 0);                                                               \
    } while (0)

#define COMPUTE(buf)                                                                 \
    do {                                                                             \
        short8 av[4], bv[4];                                                         \
        _Pragma("unroll") for (int m = 0; m < 4; m++)                                \
            av[m] = *(const short8*)&As[buf][arow + m * 512];                        \
        _Pragma("unroll") for (int n = 0; n < 4; n++)                                \
            bv[n] = *(const short8*)&Bs[buf][brow + n * 512];                        \
        _Pragma("unroll") for (int m = 0; m < 4; m++)                                \
            _Pragma("unroll") for (int n = 0; n < 4; n++)                            \
                acc[m][n] = __builtin_amdgcn_mfma_f32_16x16x32_bf16(av[m], bv[n],    \
                                                                    acc[m][n], 0, 0, 0); \
    } while (0)

    STAGE(0, 0);
    if (NSTEPS > 1) STAGE(1, 32);
#pragma unroll
    for (int s = 0; s < NSTEPS; ++s) {
        if (s + 2 < NSTEPS) {
            STAGE((s + 2) % 3, (s + 2) * 32);
            WAITV(8);                      // oldest 4 (tile s) complete; 8 in flight
        } else if (s + 1 < NSTEPS) {
            WAITV(4);
        } else {
            WAITV(0);
        }
        __builtin_amdgcn_s_barrier();      // tile s visible to all waves
        COMPUTE(s % 3);
        __builtin_amdgcn_s_barrier();      // reads done before buf reuse
    }
#undef STAGE
#undef COMPUTE

    const int crow0 = bm + wr * 64 + (lane >> 4) * 4;
    const int ccol0 = bn + wc * 64 + (lane & 15);
#pragma unroll
    for (int m = 0; m < 4; m++)
#pragma unroll
        for (int n = 0; n < 4; n++) {
            const int col = ccol0 + n * 16;
#pragma unroll
            for (int r = 0; r < 4; r++) {
                const int row = crow0 + m * 16 + r;
                const float v = acc[m][n][r];
                if (EPI == 1) {
                    if (col < DI)
                        ((u16*)C0)[(size_t)row * DI + col] = f2b(v);
                    else
                        ((u16*)C1)[(size_t)row * DI + col - DI] = f2b(siluf_(v));
                } else if (EPI == 2) {
                    u16* C0z = (u16*)C0 + (size_t)blockIdx.z * M * nreal;
                    if (col < nreal) C0z[(size_t)row * nreal + col] = f2b(v);
                } else {
                    float* C0z = (float*)C0 + (size_t)blockIdx.z * M * nreal;
                    if (col < nreal) C0z[(size_t)row * nreal + col] = v;
                }
            }
        }
}

// ---------------- fp32 GEMM 128x128 tile, 8x8 micro, BK=16: dt path (K=64) -------
// LDS padded to [16][132] (writes conflict-free). dtxs packed u32 out.
__global__ __launch_bounds__(256) void gemm128_dt(const float* __restrict__ A,
                                                  const float* __restrict__ B,
                                                  const float* __restrict__ bias,
                                                  const u16* __restrict__ xsb,
                                                  unsigned* __restrict__ dtxs,
                                                  int N, int K, int lda) {
    __shared__ float As[16][132];
    __shared__ float Bs[16][132];
    const int tid = threadIdx.x;
    const int bm = blockIdx.y * 128, bn = blockIdx.x * 128;
    const int ty = tid >> 4, tx = tid & 15;
    float acc[8][8];
#pragma unroll
    for (int i = 0; i < 8; i++)
#pragma unroll
        for (int j = 0; j < 8; j++) acc[i][j] = 0.f;

    const int ar = tid >> 2, ak = (tid & 3) << 2;
    const int bk = tid >> 5, bc = (tid & 31) << 2;

    for (int k0 = 0; k0 < K; k0 += 16) {
        float4 a0 = *(const float4*)&A[(size_t)(bm + ar) * lda + k0 + ak];
        float4 a1 = *(const float4*)&A[(size_t)(bm + ar + 64) * lda + k0 + ak];
        float4 b0 = *(const float4*)&B[(size_t)(k0 + bk) * N + bn + bc];
        float4 b1 = *(const float4*)&B[(size_t)(k0 + bk + 8) * N + bn + bc];
        __syncthreads();
        As[ak + 0][ar] = a0.x; As[ak + 1][ar] = a0.y;
        As[ak + 2][ar] = a0.z; As[ak + 3][ar] = a0.w;
        As[ak + 0][ar + 64] = a1.x; As[ak + 1][ar + 64] = a1.y;
        As[ak + 2][ar + 64] = a1.z; As[ak + 3][ar + 64] = a1.w;
        *(float4*)&Bs[bk][bc] = b0;
        *(float4*)&Bs[bk + 8][bc] = b1;
        __syncthreads();
#pragma unroll
        for (int k = 0; k < 16; k++) {
            float a[8], b[8];
            *(float4*)&a[0] = *(const float4*)&As[k][ty * 8];
            *(float4*)&a[4] = *(const float4*)&As[k][ty * 8 + 4];
            *(float4*)&b[0] = *(const float4*)&Bs[k][tx * 8];
            *(float4*)&b[4] = *(const float4*)&Bs[k][tx * 8 + 4];
#pragma unroll
            for (int i = 0; i < 8; i++)
#pragma unroll
                for (int j = 0; j < 8; j++) acc[i][j] = fmaf(a[i], b[j], acc[i][j]);
        }
    }
#pragma unroll
    for (int i = 0; i < 8; i++) {
        const int row = bm + ty * 8 + i;
#pragma unroll
        for (int j = 0; j < 8; j += 4) {
            const int col = bn + tx * 8 + j;
            const float4 bi = *(const float4*)&bias[col];
            ushort4 xv = *(const ushort4*)&xsb[(size_t)row * N + col];
            unsigned o[4];
            o[0] = (unsigned)f2b(softplus_fast(acc[i][j + 0] + bi.x)) |
                   ((unsigned)xv.x << 16);
            o[1] = (unsigned)f2b(softplus_fast(acc[i][j + 1] + bi.y)) |
                   ((unsigned)xv.y << 16);
            o[2] = (unsigned)f2b(softplus_fast(acc[i][j + 2] + bi.z)) |
                   ((unsigned)xv.z << 16);
            o[3] = (unsigned)f2b(softplus_fast(acc[i][j + 3] + bi.w)) |
                   ((unsigned)xv.w << 16);
            *(uint4*)&dtxs[(size_t)row * N + col] = *(uint4*)o;
        }
    }
}

// ---------------- sum of 4 bf16 split-K partials -> f32 out (us8 loads) ----------
__global__ __launch_bounds__(256) void sum4b(const u16* __restrict__ p,
                                             float* __restrict__ out, int n) {
    const int i = (blockIdx.x * 256 + threadIdx.x) * 8;
    us8 a = *(const us8*)&p[i];
    us8 b = *(const us8*)&p[(size_t)n + i];
    us8 c = *(const us8*)&p[2 * (size_t)n + i];
    us8 d = *(const us8*)&p[3 * (size_t)n + i];
    float o[8];
#pragma unroll
    for (int q = 0; q < 8; q++)
        o[q] = (b2f(a[q]) + b2f(b[q])) + (b2f(c[q]) + b2f(d[q]));
    *(float4*)&out[i] = *(float4*)&o[0];
    *(float4*)&out[i + 4] = *(float4*)&o[4];
}

// ---------------- reduce 16 split-K partials [z][L][96] -> xdbl [L][96] ----------
__global__ __launch_bounds__(256) void g2reduce(const float* __restrict__ part,
                                                float* __restrict__ xdbl) {
    const int gid = blockIdx.x * 256 + threadIdx.x;
    if (gid < LL * NXDBL) {
        float s = 0.f;
#pragma unroll
        for (int z = 0; z < 16; z++) s += part[(size_t)z * LL * NXDBL + gid];
        xdbl[gid] = s;
    }
}

// ---- conv (k=4, causal) + silu, 8 d/thread, us8 (16B) loads/stores ----
__global__ __launch_bounds__(256) void conv_silu(const u16* __restrict__ xcb,
                                                 const float* __restrict__ cw,
                                                 const float* __restrict__ cb,
                                                 u16* __restrict__ xsb) {
    const int gid = (blockIdx.x * 256 + threadIdx.x) * 8;  // l*DI + d (d mult of 8)
    const int l = gid >> 11;
    const int d = gid & (DI - 1);
    float acc[8];
    {
        float4 b0 = *(const float4*)&cb[d];
        float4 b1 = *(const float4*)&cb[d + 4];
        acc[0] = b0.x; acc[1] = b0.y; acc[2] = b0.z; acc[3] = b0.w;
        acc[4] = b1.x; acc[5] = b1.y; acc[6] = b1.z; acc[7] = b1.w;
    }
    float4 w[8];
#pragma unroll
    for (int q = 0; q < 8; q++) w[q] = *(const float4*)&cw[(d + q) * 4];
#pragma unroll
    for (int j = 0; j < 4; j++) {
        const int li = l + j - 3;
        if (li >= 0) {
            us8 v = *(const us8*)&xcb[(size_t)li * DI + d];
            const float wj0[8] = {((const float*)&w[0])[j], ((const float*)&w[1])[j],
                                  ((const float*)&w[2])[j], ((const float*)&w[3])[j],
                                  ((const float*)&w[4])[j], ((const float*)&w[5])[j],
                                  ((const float*)&w[6])[j], ((const float*)&w[7])[j]};
#pragma unroll
            for (int q = 0; q < 8; q++) acc[q] = fmaf(b2f(v[q]), wj0[q], acc[q]);
        }
    }
    u16 ob[8];
#pragma unroll
    for (int q = 0; q < 8; q++) ob[q] = f2b(siluf_(acc[q]));
    *(us8*)&xsb[gid] = *(us8*)ob;
}

// ---------------- scan phase 1: per-chunk composition -> bf16 chA/chB ------------
// dtxs packed u32: dt bf16 low, xs bf16 high -- single 4B coalesced load per (l,d).
__global__ __launch_bounds__(256) void scan_phase1(const unsigned* __restrict__ dtxs,
                                                   const float* __restrict__ xdbl,
                                                   const float* __restrict__ A_log,
                                                   u16* __restrict__ chA,
                                                   u16* __restrict__ chB) {
    const int g = blockIdx.x * 256 + threadIdx.x;
    const int d = g & (DI - 1);
    const int c = g >> 11;
    float An2[NS], ap[NS], bc[NS];
    {
        float al[NS];
#pragma unroll
        for (int q = 0; q < 4; q++)
            *(float4*)&al[q * 4] = *(const float4*)&A_log[d * NS + q * 4];
#pragma unroll
        for (int n = 0; n < NS; n++) {
            An2[n] = -__expf(al[n]) * 1.44269504f;
            ap[n] = 1.f;
            bc[n] = 0.f;
        }
    }
    const int l0 = c * CHLEN;
    for (int l = l0; l < l0 + CHLEN; ++l) {
        const unsigned dx2 = dtxs[(size_t)l * DI + d];
        const float dtv = b2f((u16)(dx2 & 0xffff));
        const float xsv = b2f((u16)(dx2 >> 16));
        const float dx = dtv * xsv;
        float bv[NS];
#pragma unroll
        for (int q = 0; q < 4; q++)
            *(float4*)&bv[q * 4] = *(const float4*)&xdbl[(size_t)l * NXDBL + DTR + q * 4];
#pragma unroll
        for (int n = 0; n < NS; n++) {
            const float al = __builtin_amdgcn_exp2f(dtv * An2[n]);
            ap[n] *= al;
            bc[n] = fmaf(al, bc[n], dx * bv[n]);
        }
    }
    const size_t o = ((size_t)c * DI + d) * NS;  // u16 units
    u16 ta[NS], tb[NS];
#pragma unroll
    for (int n = 0; n < NS; n++) { ta[n] = f2b(ap[n]); tb[n] = f2b(bc[n]); }
    *(us8*)&chA[o] = *(us8*)&ta[0];
    *(us8*)&chA[o + 8] = *(us8*)&ta[8];
    *(us8*)&chB[o] = *(us8*)&tb[0];
    *(us8*)&chB[o + 8] = *(us8*)&tb[8];
}

// ---------------- scan phase 2a: within-super prefix (2 states/thread) -----------
// For super s, chunks [s*8, s*8+8): replace chA/chB with the affine prefix
// (A_pre,B_pre) over earlier chunks in the super (identity for first chunk),
// and write per-super totals to supA/supB (f32).
__global__ __launch_bounds__(256) void scan_phase2a(u16* __restrict__ chA,
                                                    u16* __restrict__ chB,
                                                    float* __restrict__ supA,
                                                    float* __restrict__ supB) {
    const int G = blockIdx.x * 256 + threadIdx.x;     // [0, NSUPER * DI*NS/2)
    const int s = G >> 14;                            // / (DI*NS/2 = 16384)
    const int p = G & 16383;
    const size_t base = (size_t)2 * p;
    float af0 = 1.f, bf0 = 0.f, af1 = 1.f, bf1 = 0.f;
#pragma unroll
    for (int k = 0; k < SUBCH; ++k) {
        const int c = s * SUBCH + k;
        const size_t o = (size_t)c * DI * NS + base;
        const unsigned av = *(const unsigned*)&chA[o];
        const unsigned bvv = *(const unsigned*)&chB[o];
        *(unsigned*)&chA[o] = pack2(af0, af1);        // A_pre before chunk c
        *(unsigned*)&chB[o] = pack2(bf0, bf1);        // B_pre before chunk c
        const float a0 = b2f((u16)(av & 0xffff)), a1 = b2f((u16)(av >> 16));
        const float b0 = b2f((u16)(bvv & 0xffff)), b1 = b2f((u16)(bvv >> 16));
        bf0 = fmaf(a0, bf0, b0); af0 *= a0;
        bf1 = fmaf(a1, bf1, b1); af1 *= a1;
    }
    const size_t so = (size_t)s * (DI * NS) + base;
    *(float2*)&supA[so] = make_float2(af0, af1);
    *(float2*)&supB[so] = make_float2(bf0, bf1);
}

// ---------------- scan phase 2b: serial prefix over supers (16 iters) ------------
__global__ __launch_bounds__(256) void scan_phase2b(const float* __restrict__ supA,
                                                    const float* __restrict__ supB,
                                                    float* __restrict__ supH,
                                                    float* __restrict__ hT_out) {
    const int p = blockIdx.x * 256 + threadIdx.x;     // [0, DI*NS/2)
    const size_t base = (size_t)2 * p;
    float h0f = 0.f, h1f = 0.f;
#pragma unroll
    for (int s = 0; s < NSUPER; ++s) {
        const size_t o = (size_t)s * (DI * NS) + base;
        const float2 a = *(const float2*)&supA[o];
        const float2 b = *(const float2*)&supB[o];
        *(float2*)&supH[o] = make_float2(h0f, h1f);   // h at start of super s
        h0f = fmaf(a.x, h0f, b.x);
        h1f = fmaf(a.y, h1f, b.y);
    }
    *(float2*)&hT_out[base] = make_float2(h0f, h1f);
}

// ---------------- scan phase 3: h0 = A_pre*h_super + B_pre; fused y epilogue -----
__global__ __launch_bounds__(256) void scan_phase3(const unsigned* __restrict__ dtxs,
                                                   const float* __restrict__ xdbl,
                                                   const float* __restrict__ A_log,
                                                   const u16* __restrict__ chA,
                                                   const u16* __restrict__ chB,
                                                   const float* __restrict__ supH,
                                                   const float* __restrict__ Dw,
                                                   const u16* __restrict__ gate,
                                                   u16* __restrict__ yb) {
    const int g = blockIdx.x * 256 + threadIdx.x;
    const int d = g & (DI - 1);
    const int c = g >> 11;
    const int s = c >> 3;   // super index
    float An2[NS], h[NS];
    {
        float al[NS];
#pragma unroll
        for (int q = 0; q < 4; q++)
            *(float4*)&al[q * 4] = *(const float4*)&A_log[d * NS + q * 4];
#pragma unroll
        for (int n = 0; n < NS; n++) An2[n] = -__expf(al[n]) * 1.44269504f;
    }
    {
        const size_t ho = ((size_t)c * DI + d) * NS;       // u16 units
        const size_t so = ((size_t)s * DI + d) * NS;       // f32 units
        us8 ap0 = *(const us8*)&chA[ho];
        us8 ap1 = *(const us8*)&chA[ho + 8];
        us8 bp0 = *(const us8*)&chB[ho];
        us8 bp1 = *(const us8*)&chB[ho + 8];
        float sh[NS];
#pragma unroll
        for (int q = 0; q < 4; q++)
            *(float4*)&sh[q * 4] = *(const float4*)&supH[so + q * 4];
#pragma unroll
        for (int q = 0; q < 8; q++) {
            h[q] = fmaf(b2f((u16)ap0[q]), sh[q], b2f((u16)bp0[q]));
            h[8 + q] = fmaf(b2f((u16)ap1[q]), sh[8 + q], b2f((u16)bp1[q]));
        }
    }
    const float Dd = Dw[d];
    const int l0 = c * CHLEN;
    for (int l = l0; l < l0 + CHLEN; ++l) {
        const unsigned dx2 = dtxs[(size_t)l * DI + d];
        const float dtv = b2f((u16)(dx2 & 0xffff));
        const float xsv = b2f((u16)(dx2 >> 16));
        const float gv = b2f(gate[(size_t)l * DI + d]);
        const float dx = dtv * xsv;
        float bv[NS], cv[NS];
#pragma unroll
        for (int q = 0; q < 4; q++) {
            *(float4*)&bv[q * 4] = *(const float4*)&xdbl[(size_t)l * NXDBL + DTR + q * 4];
            *(float4*)&cv[q * 4] =
                *(const float4*)&xdbl[(size_t)l * NXDBL + DTR + NS + q * 4];
        }
#pragma unroll
        for (int n = 0; n < NS; n++) {
            const float al = __builtin_amdgcn_exp2f(dtv * An2[n]);
            h[n] = fmaf(al, h[n], dx * bv[n]);
        }
        float y0 = 0.f, y1 = 0.f, y2 = 0.f, y3 = 0.f;
#pragma unroll
        for (int n = 0; n < NS; n += 4) {
            y0 = fmaf(h[n + 0], cv[n + 0], y0);
            y1 = fmaf(h[n + 1], cv[n + 1], y1);
            y2 = fmaf(h[n + 2], cv[n + 2], y2);
            y3 = fmaf(h[n + 3], cv[n + 3], y3);
        }
        const float yv = (((y0 + y1) + (y2 + y3)) + xsv * Dd) * gv;
        yb[(size_t)l * DI + d] = f2b(yv);
    }
}

extern "C" void kernel_launch(void* const* d_in, const int* in_sizes, int n_in,
                              void* d_out, int out_size, void* d_ws, size_t ws_size,
                              hipStream_t stream) {
    const float* x = (const float*)d_in[0];
    const float* W_in = (const float*)d_in[1];
    const float* conv_w = (const float*)d_in[2];
    const float* conv_b = (const float*)d_in[3];
    const float* W_x = (const float*)d_in[4];
    const float* W_dt = (const float*)d_in[5];
    const float* b_dt = (const float*)d_in[6];
    const float* A_log = (const float*)d_in[7];
    const float* Dw = (const float*)d_in[8];
    const float* W_out = (const float*)d_in[9];
    float* out = (float*)d_out;

    // Flat workspace map (no aliasing), offsets in FLOATS.
    float* ws = (float*)d_ws;
    u16*      xcb      = (u16*)ws;               // L*DI bf16
    u16*      gate     = (u16*)(ws + 4194304);   // L*DI bf16
    unsigned* dtxs     = (unsigned*)(ws + 8388608);  // L*DI u32
    float*    xdbl     = ws + 16777216;          // L*96 f32
    u16*      chA      = (u16*)(ws + 16973824);  // NCHUNK*DI*NS bf16 (-> A_pre)
    u16*      chB      = (u16*)(ws + 21168128);  // NCHUNK*DI*NS bf16 (-> B_pre)
    u16*      xb       = (u16*)(ws + 25362432);  // L*DM bf16
    u16*      W_inT_b  = (u16*)(ws + 26411008);  // 2DI*DM bf16
    u16*      W_outT_b = (u16*)(ws + 28508160);  // DM*DI bf16
    u16*      xs_b     = (u16*)(ws + 29556736);  // L*DI bf16
    u16*      W_xT_pad = (u16*)(ws + 31653888);  // 128*DI bf16
    float*    g2part   = ws + 31784960;          // 16*L*96 f32
    u16*      g4part   = (u16*)(ws + 35979264);  // 4*L*DM bf16
    u16*      yb       = (u16*)(ws + 44367872);  // L*DI bf16 (ends 46465024)
    float*    supA     = ws + 46465024;          // NSUPER*DI*NS f32 (524288)
    float*    supB     = ws + 46989312;          // NSUPER*DI*NS f32
    float*    supH     = ws + 47513600;          // NSUPER*DI*NS f32 (ends 48037888)

    // 1) fused prep: x->bf16, W_in^T, W_out^T, W_x^T(+pad) in ONE launch
    prep_all<<<PREP_BLOCKS, 256, 0, stream>>>(x, xb, W_in, W_inT_b, W_out, W_outT_b,
                                              W_x, W_xT_pad);
    // 2) x_and_res = x @ W_in  (bf16 MFMA) -> xcb (bf16), gate = silu(res) (bf16)
    gemm_mfma<1, DM / 32><<<dim3(2 * DI / 128, LL / 128), 256, 0, stream>>>(
        xb, W_inT_b, xcb, gate, LL, 2 * DI, DM, 2 * DI);
    // 3) conv + silu -> xs_b (bf16), 8 d/thread us8
    conv_silu<<<(LL * DI) / 2048, 256, 0, stream>>>(xcb, conv_w, conv_b, xs_b);
    // 4) x_dbl = xs @ W_x  (bf16 MFMA, split-K=16 over z, N padded to 128)
    gemm_mfma<0, 4><<<dim3(1, LL / 128, 16), 256, 0, stream>>>(
        xs_b, W_xT_pad, g2part, nullptr, LL, 128, DI, NXDBL);
    g2reduce<<<(LL * NXDBL + 255) / 256, 256, 0, stream>>>(g2part, xdbl);
    // 5) dt = softplus(dt_r @ W_dt + b_dt), packed with xs into dtxs (u32)
    gemm128_dt<<<dim3(DI / 128, LL / 128), 256, 0, stream>>>(xdbl, W_dt, b_dt, xs_b,
                                                             dtxs, DI, DTR, NXDBL);
    // 6) two-level chunked scan
    scan_phase1<<<(DI * NCHUNK) / 256, 256, 0, stream>>>(dtxs, xdbl, A_log, chA, chB);
    scan_phase2a<<<(NSUPER * DI * NS / 2) / 256, 256, 0, stream>>>(chA, chB, supA,
                                                                   supB);
    scan_phase2b<<<(DI * NS / 2) / 256, 256, 0, stream>>>(supA, supB, supH,
                                                          out + (size_t)LL * DM);
    scan_phase3<<<(DI * NCHUNK) / 256, 256, 0, stream>>>(dtxs, xdbl, A_log, chA, chB,
                                                         supH, Dw, gate, yb);
    // 7) out = y @ W_out (bf16 MFMA, split-K=4 over z, bf16 partials)
    gemm_mfma<2, DI / 128><<<dim3(DM / 128, LL / 128, 4), 256, 0, stream>>>(
        yb, W_outT_b, g4part, nullptr, LL, DM, DI, DM);
    sum4b<<<(LL * DM) / 2048, 256, 0, stream>>>(g4part, out, LL * DM);
}

// Round 19
// 161.917 us; speedup vs baseline: 1.0423x; 1.0423x over previous
//
#include <hip/hip_runtime.h>
#include <math.h>

#define DM 1024
#define DI 2048
#define NS 16
#define DTR 64
#define LL 2048
#define NXDBL 96      // DTR + 2*NS
#define NCHUNK 128
#define CHLEN 16      // LL / NCHUNK

typedef unsigned short u16;
typedef __attribute__((ext_vector_type(8))) short short8;
typedef __attribute__((ext_vector_type(8))) unsigned short us8;
typedef __attribute__((ext_vector_type(4))) float f32x4;

__device__ __forceinline__ float sigmoidf_(float x) { return 1.f / (1.f + __expf(-x)); }
__device__ __forceinline__ float siluf_(float x) { return x * sigmoidf_(x); }
__device__ __forceinline__ float softplus_fast(float x) {
    return fmaxf(x, 0.f) + __logf(1.f + __expf(-fabsf(x)));
}
__device__ __forceinline__ u16 f2b(float f) {  // fp32 -> bf16 RNE
    unsigned u = __float_as_uint(f);
    return (u16)((u + 0x7FFFu + ((u >> 16) & 1u)) >> 16);
}
__device__ __forceinline__ float b2f(u16 h) {
    return __uint_as_float(((unsigned)h) << 16);
}
__device__ __forceinline__ unsigned pack2(float lo, float hi) {
    return (unsigned)f2b(lo) | ((unsigned)f2b(hi) << 16);
}

// ---------------- fused prep: x->bf16, W_in^T, W_out^T, W_x^T + zero-pad --------
__device__ __forceinline__ void convT_dev(const float* __restrict__ src,
                                          u16* __restrict__ dst, int R, int C,
                                          int bflat, int gridx, float (*t)[33]) {
    const int tx = threadIdx.x & 31, ty = threadIdx.x >> 5;  // ty 0..7
    const int c0 = (bflat % gridx) * 32, r0 = (bflat / gridx) * 32;
#pragma unroll
    for (int i = 0; i < 4; i++)
        t[ty + i * 8][tx] = src[(size_t)(r0 + ty + i * 8) * C + c0 + tx];
    __syncthreads();
#pragma unroll
    for (int i = 0; i < 4; i++)
        dst[(size_t)(c0 + ty + i * 8) * R + r0 + tx] = f2b(t[tx][ty + i * 8]);
}

// block ranges: [0,2048) x-convert | [2048,6144) W_in^T | [6144,8192) W_out^T |
//               [8192,8384) W_x^T | [8384,8640) zero-pad rows 96..127
#define PREP_BLOCKS 8640
__global__ __launch_bounds__(256) void prep_all(const float* __restrict__ x,
                                                u16* __restrict__ xb,
                                                const float* __restrict__ W_in,
                                                u16* __restrict__ W_inT,
                                                const float* __restrict__ W_out,
                                                u16* __restrict__ W_outT,
                                                const float* __restrict__ W_x,
                                                u16* __restrict__ W_xT_pad) {
    __shared__ float t[32][33];
    const int b = blockIdx.x;
    if (b < 2048) {
        const int i = (b * 256 + threadIdx.x) * 4;
        float4 v = *(const float4*)&x[i];
        u16 o[4] = {f2b(v.x), f2b(v.y), f2b(v.z), f2b(v.w)};
        *(ushort4*)&xb[i] = *(ushort4*)o;
    } else if (b < 6144) {
        convT_dev(W_in, W_inT, DM, 2 * DI, b - 2048, 2 * DI / 32, t);
    } else if (b < 8192) {
        convT_dev(W_out, W_outT, DI, DM, b - 6144, DM / 32, t);
    } else if (b < 8384) {
        convT_dev(W_x, W_xT_pad, DI, NXDBL, b - 8192, NXDBL / 32, t);
    } else {
        const int i = (b - 8384) * 256 + threadIdx.x;
        if (i < 32 * DI) W_xT_pad[96 * DI + i] = 0;
    }
}

// ---------------- bf16 MFMA GEMM: C[M][N] = A[M][K] @ Bt[N][K]^T -----------------
// 128x128 tile, BK=32, K = NSTEPS*32. 3-buffer LDS pipeline, prefetch distance 2,
// counted s_waitcnt vmcnt(N) + raw s_barrier. LDS k-group XOR swizzle on the
// per-lane GLOBAL source (write) and the ds_read offset (read); LDS stays linear.
// XCD-aware block swizzle: flat id -> (h&7)*(nb/8)+(h>>3), column-major decompose.
// EPI==1: cols [0,DI) -> C0 as bf16 (u16); cols [DI,2DI) -> C1 f32 (res), ld=DI.
// EPI==0: fp32 partial to (float*)C0 + z*M*nreal, ld=nreal, store iff col<nreal.
// EPI==2: bf16 partial to (u16*)C0 + z*M*nreal, ld=nreal.
#define WAITV(N) asm volatile("s_waitcnt vmcnt(" #N ")" ::: "memory")
template <int EPI, int NSTEPS>
__global__ __launch_bounds__(256) void gemm_mfma(const u16* __restrict__ A,
                                                 const u16* __restrict__ Bt,
                                                 void* __restrict__ C0,
                                                 void* __restrict__ C1,
                                                 int M, int N, int lda, int nreal) {
    __shared__ u16 As[3][128 * 32];
    __shared__ u16 Bs[3][128 * 32];
    const int tid = threadIdx.x;
    const int lane = tid & 63;
    const int wave = tid >> 6;
    // XCD-aware swizzle (bijective; nb multiple of 8)
    const int gx = gridDim.x, gy = gridDim.y;
    const int nb = gx * gy;
    const int h = blockIdx.y * gx + blockIdx.x;
    const int f = (h & 7) * (nb >> 3) + (h >> 3);
    const int bm = (f % gy) * 128, bn = (f / gy) * 128;
    const int wr = wave >> 1, wc = wave & 1;
    const int k_off = blockIdx.z * (NSTEPS * 32);

    f32x4 acc[4][4];
#pragma unroll
    for (int m = 0; m < 4; m++)
#pragma unroll
        for (int n = 0; n < 4; n++) acc[m][n] = (f32x4)0.f;

    // staging: thread tid -> (row = tid>>2, kg = tid&3), LDS linear at tid*16B.
    const int srow = tid >> 2;
    const int swz = (tid >> 3) & 3;                    // (srow>>1)&3
    const int skel = (((tid & 3) ^ swz) << 3);         // swizzled k elem offset
    const u16* Ag0 = A + (size_t)(bm + srow) * lda + k_off + skel;
    const u16* Ag1 = A + (size_t)(bm + 64 + srow) * lda + k_off + skel;
    const u16* Bg0 = Bt + (size_t)(bn + srow) * lda + k_off + skel;
    const u16* Bg1 = Bt + (size_t)(bn + 64 + srow) * lda + k_off + skel;
    u16* Asl = &As[0][0] + tid * 8;
    u16* Bsl = &Bs[0][0] + tid * 8;

    // fragment read offsets (u16 units), same swizzle on the kg index
    const int rsw = (lane >> 1) & 3;                   // row bits 1-2
    const int arow = (wr * 64 + (lane & 15)) * 32 + (((lane >> 4) ^ rsw) << 3);
    const int brow = (wc * 64 + (lane & 15)) * 32 + (((lane >> 4) ^ rsw) << 3);

#define STAGE(buf, ks)                                                               \
    do {                                                                             \
        __builtin_amdgcn_global_load_lds(                                            \
            (const __attribute__((address_space(1))) unsigned*)(Ag0 + (ks)),         \
            (__attribute__((address_space(3))) unsigned*)(Asl + (buf) * 4096),       \
            16, 0, 0);                                                               \
        __builtin_amdgcn_global_load_lds(                                            \
            (const __attribute__((address_space(1))) unsigned*)(Ag1 + (ks)),         \
            (__attribute__((address_space(3))) unsigned*)(Asl + (buf) * 4096 + 2048),\
            16, 0, 0);                                                               \
        __builtin_amdgcn_global_load_lds(                                            \
            (const __attribute__((address_space(1))) unsigned*)(Bg0 + (ks)),         \
            (__attribute__((address_space(3))) unsigned*)(Bsl + (buf) * 4096),       \
            16, 0, 0);                                                               \
        __builtin_amdgcn_global_load_lds(                                            \
            (const __attribute__((address_space(1))) unsigned*)(Bg1 + (ks)),         \
            (__attribute__((address_space(3))) unsigned*)(Bsl + (buf) * 4096 + 2048),\
            16, 0, 0);                                                               \
    } while (0)

#define COMPUTE(buf)                                                                 \
    do {                                                                             \
        short8 av[4], bv[4];                                                         \
        _Pragma("unroll") for (int m = 0; m < 4; m++)                                \
            av[m] = *(const short8*)&As[buf][arow + m * 512];                        \
        _Pragma("unroll") for (int n = 0; n < 4; n++)                                \
            bv[n] = *(const short8*)&Bs[buf][brow + n * 512];                        \
        _Pragma("unroll") for (int m = 0; m < 4; m++)                                \
            _Pragma("unroll") for (int n = 0; n < 4; n++)                            \
                acc[m][n] = __builtin_amdgcn_mfma_f32_16x16x32_bf16(av[m], bv[n],    \
                                                                    acc[m][n], 0, 0, 0); \
    } while (0)

    STAGE(0, 0);
    if (NSTEPS > 1) STAGE(1, 32);
#pragma unroll
    for (int s = 0; s < NSTEPS; ++s) {
        if (s + 2 < NSTEPS) {
            STAGE((s + 2) % 3, (s + 2) * 32);
            WAITV(8);                      // oldest 4 (tile s) complete; 8 in flight
        } else if (s + 1 < NSTEPS) {
            WAITV(4);
        } else {
            WAITV(0);
        }
        __builtin_amdgcn_s_barrier();      // tile s visible to all waves
        COMPUTE(s % 3);
        __builtin_amdgcn_s_barrier();      // reads done before buf reuse
    }
#undef STAGE
#undef COMPUTE

    const int crow0 = bm + wr * 64 + (lane >> 4) * 4;
    const int ccol0 = bn + wc * 64 + (lane & 15);
#pragma unroll
    for (int m = 0; m < 4; m++)
#pragma unroll
        for (int n = 0; n < 4; n++) {
            const int col = ccol0 + n * 16;
#pragma unroll
            for (int r = 0; r < 4; r++) {
                const int row = crow0 + m * 16 + r;
                const float v = acc[m][n][r];
                if (EPI == 1) {
                    if (col < DI)
                        ((u16*)C0)[(size_t)row * DI + col] = f2b(v);
                    else
                        ((float*)C1)[(size_t)row * DI + col - DI] = v;
                } else if (EPI == 2) {
                    u16* C0z = (u16*)C0 + (size_t)blockIdx.z * M * nreal;
                    if (col < nreal) C0z[(size_t)row * nreal + col] = f2b(v);
                } else {
                    float* C0z = (float*)C0 + (size_t)blockIdx.z * M * nreal;
                    if (col < nreal) C0z[(size_t)row * nreal + col] = v;
                }
            }
        }
}

// ---------------- fp32 GEMM 128x128 tile, 8x8 micro, BK=16: dt path (K=64) -------
// dtxs[l][d] = (bf16(softplus(A@B+bias)) ) | (xs_b[l][d] << 16)  -- packed u32.
__global__ __launch_bounds__(256) void gemm128_dt(const float* __restrict__ A,
                                                  const float* __restrict__ B,
                                                  const float* __restrict__ bias,
                                                  const u16* __restrict__ xsb,
                                                  unsigned* __restrict__ dtxs,
                                                  int N, int K, int lda) {
    __shared__ float As[16][128];
    __shared__ float Bs[16][128];
    const int tid = threadIdx.x;
    const int bm = blockIdx.y * 128, bn = blockIdx.x * 128;
    const int ty = tid >> 4, tx = tid & 15;
    float acc[8][8];
#pragma unroll
    for (int i = 0; i < 8; i++)
#pragma unroll
        for (int j = 0; j < 8; j++) acc[i][j] = 0.f;

    const int ar = tid >> 2, ak = (tid & 3) << 2;
    const int bk = tid >> 5, bc = (tid & 31) << 2;

    for (int k0 = 0; k0 < K; k0 += 16) {
        float4 a0 = *(const float4*)&A[(size_t)(bm + ar) * lda + k0 + ak];
        float4 a1 = *(const float4*)&A[(size_t)(bm + ar + 64) * lda + k0 + ak];
        float4 b0 = *(const float4*)&B[(size_t)(k0 + bk) * N + bn + bc];
        float4 b1 = *(const float4*)&B[(size_t)(k0 + bk + 8) * N + bn + bc];
        __syncthreads();
        As[ak + 0][ar] = a0.x; As[ak + 1][ar] = a0.y;
        As[ak + 2][ar] = a0.z; As[ak + 3][ar] = a0.w;
        As[ak + 0][ar + 64] = a1.x; As[ak + 1][ar + 64] = a1.y;
        As[ak + 2][ar + 64] = a1.z; As[ak + 3][ar + 64] = a1.w;
        *(float4*)&Bs[bk][bc] = b0;
        *(float4*)&Bs[bk + 8][bc] = b1;
        __syncthreads();
#pragma unroll
        for (int k = 0; k < 16; k++) {
            float a[8], b[8];
            *(float4*)&a[0] = *(const float4*)&As[k][ty * 8];
            *(float4*)&a[4] = *(const float4*)&As[k][ty * 8 + 4];
            *(float4*)&b[0] = *(const float4*)&Bs[k][tx * 8];
            *(float4*)&b[4] = *(const float4*)&Bs[k][tx * 8 + 4];
#pragma unroll
            for (int i = 0; i < 8; i++)
#pragma unroll
                for (int j = 0; j < 8; j++) acc[i][j] = fmaf(a[i], b[j], acc[i][j]);
        }
    }
#pragma unroll
    for (int i = 0; i < 8; i++) {
        const int row = bm + ty * 8 + i;
#pragma unroll
        for (int j = 0; j < 8; j += 4) {
            const int col = bn + tx * 8 + j;
            const float4 bi = *(const float4*)&bias[col];
            ushort4 xv = *(const ushort4*)&xsb[(size_t)row * N + col];
            unsigned o[4];
            o[0] = (unsigned)f2b(softplus_fast(acc[i][j + 0] + bi.x)) |
                   ((unsigned)xv.x << 16);
            o[1] = (unsigned)f2b(softplus_fast(acc[i][j + 1] + bi.y)) |
                   ((unsigned)xv.y << 16);
            o[2] = (unsigned)f2b(softplus_fast(acc[i][j + 2] + bi.z)) |
                   ((unsigned)xv.z << 16);
            o[3] = (unsigned)f2b(softplus_fast(acc[i][j + 3] + bi.w)) |
                   ((unsigned)xv.w << 16);
            *(uint4*)&dtxs[(size_t)row * N + col] = *(uint4*)o;
        }
    }
}

// ---------------- sum of 4 bf16 split-K partials -> f32 out -----------------
__global__ __launch_bounds__(256) void sum4b(const u16* __restrict__ p,
                                             float* __restrict__ out, int n) {
    const int i = (blockIdx.x * 256 + threadIdx.x) * 4;
    ushort4 a = *(const ushort4*)&p[i];
    ushort4 b = *(const ushort4*)&p[(size_t)n + i];
    ushort4 c = *(const ushort4*)&p[2 * (size_t)n + i];
    ushort4 d = *(const ushort4*)&p[3 * (size_t)n + i];
    *(float4*)&out[i] = make_float4(
        (b2f(a.x) + b2f(b.x)) + (b2f(c.x) + b2f(d.x)),
        (b2f(a.y) + b2f(b.y)) + (b2f(c.y) + b2f(d.y)),
        (b2f(a.z) + b2f(b.z)) + (b2f(c.z) + b2f(d.z)),
        (b2f(a.w) + b2f(b.w)) + (b2f(c.w) + b2f(d.w)));
}

// ---------------- reduce 16 split-K partials [z][L][96] -> xdbl [L][96] ----------
__global__ __launch_bounds__(256) void g2reduce(const float* __restrict__ part,
                                                float* __restrict__ xdbl) {
    const int gid = blockIdx.x * 256 + threadIdx.x;
    if (gid < LL * NXDBL) {
        float s = 0.f;
#pragma unroll
        for (int z = 0; z < 16; z++) s += part[(size_t)z * LL * NXDBL + gid];
        xdbl[gid] = s;
    }
}

// ---- conv (k=4, causal) + silu, 4 d/thread, vectorized; bf16 out only ----
__global__ __launch_bounds__(256) void conv_silu(const u16* __restrict__ xcb,
                                                 const float* __restrict__ cw,
                                                 const float* __restrict__ cb,
                                                 u16* __restrict__ xsb) {
    const int gid = (blockIdx.x * 256 + threadIdx.x) * 4;  // l*DI + d (d multiple of 4)
    const int l = gid >> 11;
    const int d = gid & (DI - 1);
    float acc[4];
    {
        float4 b4 = *(const float4*)&cb[d];
        acc[0] = b4.x; acc[1] = b4.y; acc[2] = b4.z; acc[3] = b4.w;
    }
    float4 w0 = *(const float4*)&cw[(d + 0) * 4];
    float4 w1 = *(const float4*)&cw[(d + 1) * 4];
    float4 w2 = *(const float4*)&cw[(d + 2) * 4];
    float4 w3 = *(const float4*)&cw[(d + 3) * 4];
    const float* wp0 = (const float*)&w0;
    const float* wp1 = (const float*)&w1;
    const float* wp2 = (const float*)&w2;
    const float* wp3 = (const float*)&w3;
#pragma unroll
    for (int j = 0; j < 4; j++) {
        const int li = l + j - 3;
        if (li >= 0) {
            ushort4 v = *(const ushort4*)&xcb[(size_t)li * DI + d];
            acc[0] = fmaf(b2f(v.x), wp0[j], acc[0]);
            acc[1] = fmaf(b2f(v.y), wp1[j], acc[1]);
            acc[2] = fmaf(b2f(v.z), wp2[j], acc[2]);
            acc[3] = fmaf(b2f(v.w), wp3[j], acc[3]);
        }
    }
    u16 ob[4] = {f2b(siluf_(acc[0])), f2b(siluf_(acc[1])),
                 f2b(siluf_(acc[2])), f2b(siluf_(acc[3]))};
    *(ushort4*)&xsb[gid] = *(ushort4*)ob;
}

// ---------------- scan phase 1: per-chunk composition -> bf16 chA/chB ------------
// dtxs packed u32: dt bf16 low, xs bf16 high -- single 4B coalesced load per (l,d).
__global__ __launch_bounds__(256) void scan_phase1(const unsigned* __restrict__ dtxs,
                                                   const float* __restrict__ xdbl,
                                                   const float* __restrict__ A_log,
                                                   u16* __restrict__ chA,
                                                   u16* __restrict__ chB) {
    const int g = blockIdx.x * 256 + threadIdx.x;
    const int d = g & (DI - 1);
    const int c = g >> 11;
    float An2[NS], ap[NS], bc[NS];
    {
        float al[NS];
#pragma unroll
        for (int q = 0; q < 4; q++)
            *(float4*)&al[q * 4] = *(const float4*)&A_log[d * NS + q * 4];
#pragma unroll
        for (int n = 0; n < NS; n++) {
            An2[n] = -__expf(al[n]) * 1.44269504f;
            ap[n] = 1.f;
            bc[n] = 0.f;
        }
    }
    const int l0 = c * CHLEN;
    for (int l = l0; l < l0 + CHLEN; ++l) {
        const unsigned dx2 = dtxs[(size_t)l * DI + d];
        const float dtv = b2f((u16)(dx2 & 0xffff));
        const float xsv = b2f((u16)(dx2 >> 16));
        const float dx = dtv * xsv;
        float bv[NS];
#pragma unroll
        for (int q = 0; q < 4; q++)
            *(float4*)&bv[q * 4] = *(const float4*)&xdbl[(size_t)l * NXDBL + DTR + q * 4];
#pragma unroll
        for (int n = 0; n < NS; n++) {
            const float al = __builtin_amdgcn_exp2f(dtv * An2[n]);
            ap[n] *= al;
            bc[n] = fmaf(al, bc[n], dx * bv[n]);
        }
    }
    const size_t o = ((size_t)c * DI + d) * NS;  // u16 units
    u16 ta[NS], tb[NS];
#pragma unroll
    for (int n = 0; n < NS; n++) { ta[n] = f2b(ap[n]); tb[n] = f2b(bc[n]); }
    *(us8*)&chA[o] = *(us8*)&ta[0];
    *(us8*)&chA[o + 8] = *(us8*)&ta[8];
    *(us8*)&chB[o] = *(us8*)&tb[0];
    *(us8*)&chB[o + 8] = *(us8*)&tb[8];
}

// ---------------- scan phase 2: serial prefix over chunks, 2 states/thread -------
// chA/chB bf16; h0 written in-place into chA (packed bf16 pair); carry f32.
__global__ __launch_bounds__(256) void scan_phase2(u16* __restrict__ chA,
                                                   const u16* __restrict__ chB,
                                                   float* __restrict__ hT_out) {
    const int p = blockIdx.x * 256 + threadIdx.x;  // 0..DI*NS/2-1
    const size_t base = (size_t)2 * p;
    float h0f = 0.f, h1f = 0.f;
#pragma unroll 16
    for (int c = 0; c < NCHUNK; ++c) {
        const size_t o = (size_t)c * DI * NS + base;
        const unsigned av = *(const unsigned*)&chA[o];
        const unsigned bv = *(const unsigned*)&chB[o];
        *(unsigned*)&chA[o] = pack2(h0f, h1f);  // h0 for chunk c
        h0f = fmaf(b2f((u16)(av & 0xffff)), h0f, b2f((u16)(bv & 0xffff)));
        h1f = fmaf(b2f((u16)(av >> 16)), h1f, b2f((u16)(bv >> 16)));
    }
    *(float2*)&hT_out[base] = make_float2(h0f, h1f);
}

// ---------------- scan phase 3: re-scan with h0 (bf16), fused y epilogue ---------
__global__ __launch_bounds__(256) void scan_phase3(const unsigned* __restrict__ dtxs,
                                                   const float* __restrict__ xdbl,
                                                   const float* __restrict__ A_log,
                                                   const u16* __restrict__ h0,
                                                   const float* __restrict__ Dw,
                                                   const float* __restrict__ res,
                                                   u16* __restrict__ yb) {
    const int g = blockIdx.x * 256 + threadIdx.x;
    const int d = g & (DI - 1);
    const int c = g >> 11;
    float An2[NS], h[NS];
    {
        float al[NS];
#pragma unroll
        for (int q = 0; q < 4; q++)
            *(float4*)&al[q * 4] = *(const float4*)&A_log[d * NS + q * 4];
#pragma unroll
        for (int n = 0; n < NS; n++) An2[n] = -__expf(al[n]) * 1.44269504f;
    }
    {
        const size_t ho = ((size_t)c * DI + d) * NS;  // u16 units
        us8 h0a = *(const us8*)&h0[ho];
        us8 h0b = *(const us8*)&h0[ho + 8];
#pragma unroll
        for (int q = 0; q < 8; q++) {
            h[q] = b2f((u16)h0a[q]);
            h[8 + q] = b2f((u16)h0b[q]);
        }
    }
    const float Dd = Dw[d];
    const int l0 = c * CHLEN;
    for (int l = l0; l < l0 + CHLEN; ++l) {
        const unsigned dx2 = dtxs[(size_t)l * DI + d];
        const float dtv = b2f((u16)(dx2 & 0xffff));
        const float xsv = b2f((u16)(dx2 >> 16));
        const float resv = res[(size_t)l * DI + d];
        const float dx = dtv * xsv;
        float bv[NS], cv[NS];
#pragma unroll
        for (int q = 0; q < 4; q++) {
            *(float4*)&bv[q * 4] = *(const float4*)&xdbl[(size_t)l * NXDBL + DTR + q * 4];
            *(float4*)&cv[q * 4] =
                *(const float4*)&xdbl[(size_t)l * NXDBL + DTR + NS + q * 4];
        }
#pragma unroll
        for (int n = 0; n < NS; n++) {
            const float al = __builtin_amdgcn_exp2f(dtv * An2[n]);
            h[n] = fmaf(al, h[n], dx * bv[n]);
        }
        float y0 = 0.f, y1 = 0.f, y2 = 0.f, y3 = 0.f;
#pragma unroll
        for (int n = 0; n < NS; n += 4) {
            y0 = fmaf(h[n + 0], cv[n + 0], y0);
            y1 = fmaf(h[n + 1], cv[n + 1], y1);
            y2 = fmaf(h[n + 2], cv[n + 2], y2);
            y3 = fmaf(h[n + 3], cv[n + 3], y3);
        }
        float yv = ((y0 + y1) + (y2 + y3)) + xsv * Dd;
        yv *= siluf_(resv);
        yb[(size_t)l * DI + d] = f2b(yv);
    }
}

extern "C" void kernel_launch(void* const* d_in, const int* in_sizes, int n_in,
                              void* d_out, int out_size, void* d_ws, size_t ws_size,
                              hipStream_t stream) {
    const float* x = (const float*)d_in[0];
    const float* W_in = (const float*)d_in[1];
    const float* conv_w = (const float*)d_in[2];
    const float* conv_b = (const float*)d_in[3];
    const float* W_x = (const float*)d_in[4];
    const float* W_dt = (const float*)d_in[5];
    const float* b_dt = (const float*)d_in[6];
    const float* A_log = (const float*)d_in[7];
    const float* Dw = (const float*)d_in[8];
    const float* W_out = (const float*)d_in[9];
    float* out = (float*)d_out;

    // Flat workspace map (no aliasing), offsets in FLOATS.
    float* ws = (float*)d_ws;
    u16*      xcb      = (u16*)ws;               // L*DI bf16       (slot 4194304 f)
    float*    res      = ws + 4194304;           // L*DI f32        (4194304)
    unsigned* dtxs     = (unsigned*)(ws + 8388608);  // L*DI u32    (4194304)
    float*    xdbl     = ws + 16777216;          // L*96 f32        (196608)
    u16*      chA      = (u16*)(ws + 16973824);  // NCHUNK*DI*NS bf16 (->h0)
    u16*      chB      = (u16*)(ws + 21168128);  // NCHUNK*DI*NS bf16
    u16*      xb       = (u16*)(ws + 25362432);  // L*DM bf16       (1048576 f)
    u16*      W_inT_b  = (u16*)(ws + 26411008);  // 2DI*DM bf16     (2097152 f)
    u16*      W_outT_b = (u16*)(ws + 28508160);  // DM*DI bf16      (1048576 f)
    u16*      xs_b     = (u16*)(ws + 29556736);  // L*DI bf16       (2097152 f)
    u16*      W_xT_pad = (u16*)(ws + 31653888);  // 128*DI bf16     (131072 f)
    float*    g2part   = ws + 31784960;          // 16*L*96 f32     (3145728 f)
    u16*      g4part   = (u16*)(ws + 35979264);  // 4*L*DM bf16     (slot 8388608 f)
    u16*      yb       = (u16*)(ws + 44367872);  // L*DI bf16       (2097152 f)

    // 1) fused prep: x->bf16, W_in^T, W_out^T, W_x^T(+pad) in ONE launch
    prep_all<<<PREP_BLOCKS, 256, 0, stream>>>(x, xb, W_in, W_inT_b, W_out, W_outT_b,
                                              W_x, W_xT_pad);
    // 2) x_and_res = x @ W_in  (bf16 MFMA) -> xcb (bf16), res (f32)
    gemm_mfma<1, DM / 32><<<dim3(2 * DI / 128, LL / 128), 256, 0, stream>>>(
        xb, W_inT_b, xcb, res, LL, 2 * DI, DM, 2 * DI);
    // 3) conv + silu -> xs_b (bf16 only), 4 d/thread vectorized
    conv_silu<<<(LL * DI) / 1024, 256, 0, stream>>>(xcb, conv_w, conv_b, xs_b);
    // 4) x_dbl = xs @ W_x  (bf16 MFMA, split-K=16 over z, N padded to 128,
    //    f32 partials at true ld=96)
    gemm_mfma<0, 4><<<dim3(1, LL / 128, 16), 256, 0, stream>>>(
        xs_b, W_xT_pad, g2part, nullptr, LL, 128, DI, NXDBL);
    g2reduce<<<(LL * NXDBL + 255) / 256, 256, 0, stream>>>(g2part, xdbl);
    // 5) dt = softplus(dt_r @ W_dt + b_dt), packed with xs into dtxs (u32)
    gemm128_dt<<<dim3(DI / 128, LL / 128), 256, 0, stream>>>(xdbl, W_dt, b_dt, xs_b,
                                                             dtxs, DI, DTR, NXDBL);
    // 6) chunked scan (packed dtxs loads; bf16 chA/chB/h0, vectorized)
    scan_phase1<<<(DI * NCHUNK) / 256, 256, 0, stream>>>(dtxs, xdbl, A_log, chA, chB);
    scan_phase2<<<(DI * NS / 2) / 256, 256, 0, stream>>>(chA, chB,
                                                         out + (size_t)LL * DM);
    scan_phase3<<<(DI * NCHUNK) / 256, 256, 0, stream>>>(dtxs, xdbl, A_log, chA, Dw,
                                                         res, yb);
    // 7) out = y @ W_out (bf16 MFMA, split-K=4 over z, bf16 partials)
    gemm_mfma<2, DI / 128><<<dim3(DM / 128, LL / 128, 4), 256, 0, stream>>>(
        yb, W_outT_b, g4part, nullptr, LL, DM, DI, DM);
    sum4b<<<(LL * DM) / 1024, 256, 0, stream>>>(g4part, out, LL * DM);
}